// Round 1
// baseline (978.769 us; speedup 1.0000x reference)
//
#include <hip/hip_runtime.h>

#define D 512
#define H1 1024
#define NNODES 50000
#define NEDGES 400000
#define MPAD 50048   // 391 * 128
#define NEG_SLOPE 0.2f

typedef __attribute__((ext_vector_type(8))) short bf16x8;
typedef __attribute__((ext_vector_type(4))) float f32x4;
typedef __attribute__((ext_vector_type(4))) unsigned int u32x4;

__device__ __forceinline__ unsigned short f2bf(float f) {
  unsigned int u = __float_as_uint(f);
  unsigned int r = u + 0x7FFFu + ((u >> 16) & 1u);
  return (unsigned short)(r >> 16);
}

// key[j] = sum_i cond[i] * Wk[i][j],  Wk is (256, 2D) row-major
__global__ void key_kernel(const float* __restrict__ cond, const float* __restrict__ Wk,
                           float* __restrict__ key) {
  int j = blockIdx.x * blockDim.x + threadIdx.x;
  if (j >= 2 * D) return;
  float s = 0.f;
#pragma unroll 8
  for (int i = 0; i < 256; ++i) s += cond[i] * Wk[i * (2 * D) + j];
  key[j] = s;
}

// nki[n] = x[n] . key[0:D] ; nkj[n] = x[n] . key[D:2D]  (one wave per node)
__global__ void nodedot_kernel(const float* __restrict__ x, const float* __restrict__ key,
                               float* __restrict__ nki, float* __restrict__ nkj) {
  int wid = (blockIdx.x * blockDim.x + threadIdx.x) >> 6;
  int lane = threadIdx.x & 63;
  if (wid >= NNODES) return;
  const float* xr = x + (size_t)wid * D;
  float a = 0.f, b = 0.f;
#pragma unroll
  for (int k = 0; k < D / 64; ++k) {
    int idx = lane + k * 64;
    float v = xr[idx];
    a += v * key[idx];
    b += v * key[D + idx];
  }
#pragma unroll
  for (int off = 32; off > 0; off >>= 1) {
    a += __shfl_xor(a, off);
    b += __shfl_xor(b, off);
  }
  if (lane == 0) { nki[wid] = a; nkj[wid] = b; }
}

// out = x  (so scatter can accumulate agg on top; EPS = 0)
__global__ void init_kernel(const float* __restrict__ x, float* __restrict__ out) {
  size_t total = (size_t)NNODES * D / 4;
  const float4* src = (const float4*)x;
  float4* dst = (float4*)out;
  for (size_t i = blockIdx.x * (size_t)blockDim.x + threadIdx.x; i < total;
       i += (size_t)gridDim.x * blockDim.x)
    dst[i] = src[i];
}

// W1 (D,2D) -> W1t (2D,D) bf16 ; W2 (2D,D) -> W2t (D,2D) bf16   (N x K layouts)
__global__ void convw_kernel(const float* __restrict__ W1, const float* __restrict__ W2,
                             unsigned short* __restrict__ W1t, unsigned short* __restrict__ W2t) {
  int idx = blockIdx.x * blockDim.x + threadIdx.x;
  if (idx >= D * H1) return;
  { int k = idx / H1, n = idx % H1; W1t[(size_t)n * D + k] = f2bf(W1[idx]); }
  { int k = idx / D,  n = idx % D;  W2t[(size_t)n * H1 + k] = f2bf(W2[idx]); }
}

// one wave per edge: alpha_e = sigmoid(leaky(nki[col] + nkj[row])); out[row] += x[col]*alpha
__global__ void scatter_kernel(const float* __restrict__ x, const int* __restrict__ row,
                               const int* __restrict__ col, const float* __restrict__ nki,
                               const float* __restrict__ nkj, float* __restrict__ out) {
  int wid = (blockIdx.x * blockDim.x + threadIdx.x) >> 6;
  int lane = threadIdx.x & 63;
  if (wid >= NEDGES) return;
  int r = row[wid], c = col[wid];
  float a = nki[c] + nkj[r];
  a = (a >= 0.f) ? a : NEG_SLOPE * a;
  float al = 1.f / (1.f + expf(-a));
  const float* xs = x + (size_t)c * D;
  float* od = out + (size_t)r * D;
#pragma unroll
  for (int k = 0; k < D / 64; ++k) {
    int idx = lane + k * 64;
    atomicAdd(&od[idx], xs[idx] * al);
  }
}

// C = act(A @ Bt^T + bias). A: MxK row-major (f32 or bf16). Bt: NxK bf16 row-major.
// Tile 128x128, BK=32, 4 waves (2x2), each wave 64x64 = 4x4 tiles of 16x16x32 MFMA.
template <bool A_BF16, bool RELU_OUT_BF16>
__global__ __launch_bounds__(256) void gemm_kernel(
    const void* __restrict__ Aptr, const unsigned short* __restrict__ Bt,
    const float* __restrict__ bias, void* __restrict__ Cptr, int M_valid, int K, int N) {
  constexpr int BK = 32, BKP = 40;  // +8 pad breaks LDS bank conflicts
  __shared__ unsigned short As[128][BKP];
  __shared__ unsigned short Bs[128][BKP];

  const int tid = threadIdx.x;
  const int lane = tid & 63;
  const int wave = tid >> 6;
  const int wm = (wave >> 1) * 64;
  const int wn = (wave & 1) * 64;
  const int m0 = blockIdx.x * 128;
  const int n0 = blockIdx.y * 128;
  const int srow = tid >> 1;           // 0..127
  const int shalf = (tid & 1) * 16;    // 0 or 16 (k offset)
  const int fr = lane & 15;
  const int kg = (lane >> 4) * 8;

  f32x4 acc[4][4];
#pragma unroll
  for (int i = 0; i < 4; ++i)
#pragma unroll
    for (int j = 0; j < 4; ++j)
#pragma unroll
      for (int r = 0; r < 4; ++r) acc[i][j][r] = 0.f;

  for (int k0 = 0; k0 < K; k0 += BK) {
    {  // stage A tile [128][32]
      int gm = m0 + srow;
      if constexpr (A_BF16) {
        const unsigned short* Ah = (const unsigned short*)Aptr;
        const u32x4* s = (const u32x4*)(Ah + (size_t)gm * K + k0 + shalf);
        *(u32x4*)&As[srow][shalf] = s[0];
        *(u32x4*)&As[srow][shalf + 8] = s[1];
      } else {
        const float* Af = (const float*)Aptr;
        alignas(16) unsigned short h[16];
        if (gm < M_valid) {
          const float4* s4 = (const float4*)(Af + (size_t)gm * K + k0 + shalf);
#pragma unroll
          for (int q = 0; q < 4; ++q) {
            float4 f = s4[q];
            h[q * 4 + 0] = f2bf(f.x); h[q * 4 + 1] = f2bf(f.y);
            h[q * 4 + 2] = f2bf(f.z); h[q * 4 + 3] = f2bf(f.w);
          }
        } else {
#pragma unroll
          for (int q = 0; q < 16; ++q) h[q] = 0;
        }
        *(u32x4*)&As[srow][shalf] = *(const u32x4*)&h[0];
        *(u32x4*)&As[srow][shalf + 8] = *(const u32x4*)&h[8];
      }
      // stage B tile [128 n][32 k] from Bt (NxK)
      int gn = n0 + srow;
      const u32x4* s = (const u32x4*)(Bt + (size_t)gn * K + k0 + shalf);
      *(u32x4*)&Bs[srow][shalf] = s[0];
      *(u32x4*)&Bs[srow][shalf + 8] = s[1];
    }
    __syncthreads();

    bf16x8 a_frag[4], b_frag[4];
#pragma unroll
    for (int i = 0; i < 4; ++i) a_frag[i] = *(const bf16x8*)&As[wm + i * 16 + fr][kg];
#pragma unroll
    for (int j = 0; j < 4; ++j) b_frag[j] = *(const bf16x8*)&Bs[wn + j * 16 + fr][kg];
#pragma unroll
    for (int i = 0; i < 4; ++i)
#pragma unroll
      for (int j = 0; j < 4; ++j)
        acc[i][j] = __builtin_amdgcn_mfma_f32_16x16x32_bf16(a_frag[i], b_frag[j], acc[i][j], 0, 0, 0);
    __syncthreads();
  }

  // epilogue: C/D layout col = lane&15, row = (lane>>4)*4 + reg  [verified mapping]
  const int rg = (lane >> 4) * 4;
#pragma unroll
  for (int i = 0; i < 4; ++i) {
#pragma unroll
    for (int j = 0; j < 4; ++j) {
      int gn = n0 + wn + j * 16 + fr;
      float bv = bias[gn];
#pragma unroll
      for (int r = 0; r < 4; ++r) {
        int gm = m0 + wm + i * 16 + rg + r;
        float v = acc[i][j][r] + bv;
        if constexpr (RELU_OUT_BF16) {
          v = fmaxf(v, 0.f);
          ((unsigned short*)Cptr)[(size_t)gm * N + gn] = f2bf(v);
        } else {
          if (gm < M_valid) ((float*)Cptr)[(size_t)gm * N + gn] = v;
        }
      }
    }
  }
}

extern "C" void kernel_launch(void* const* d_in, const int* in_sizes, int n_in,
                              void* d_out, int out_size, void* d_ws, size_t ws_size,
                              hipStream_t stream) {
  const float* x    = (const float*)d_in[0];
  const int*   ei   = (const int*)d_in[1];
  const float* cond = (const float*)d_in[2];
  const float* Wk   = (const float*)d_in[3];
  const float* W1   = (const float*)d_in[4];
  const float* b1   = (const float*)d_in[5];
  const float* W2   = (const float*)d_in[6];
  const float* b2   = (const float*)d_in[7];
  float* out = (float*)d_out;

  char* ws = (char*)d_ws;
  size_t off = 0;
  auto alloc = [&](size_t b) { size_t p = off; off += (b + 255) & ~(size_t)255; return p; };
  float* key = (float*)(ws + alloc(2 * D * sizeof(float)));
  float* nki = (float*)(ws + alloc(NNODES * sizeof(float)));
  float* nkj = (float*)(ws + alloc(NNODES * sizeof(float)));
  unsigned short* W1t = (unsigned short*)(ws + alloc((size_t)H1 * D * 2));      // (2D, D)
  unsigned short* W2t = (unsigned short*)(ws + alloc((size_t)D * H1 * 2));      // (D, 2D)
  unsigned short* Hb  = (unsigned short*)(ws + alloc((size_t)MPAD * H1 * 2));   // hidden, bf16

  const int* row = ei;
  const int* col = ei + NEDGES;

  key_kernel<<<dim3((2 * D + 255) / 256), dim3(256), 0, stream>>>(cond, Wk, key);
  nodedot_kernel<<<dim3(NNODES * 64 / 256), dim3(256), 0, stream>>>(x, key, nki, nkj);
  init_kernel<<<dim3(2048), dim3(256), 0, stream>>>(x, out);
  convw_kernel<<<dim3(D * H1 / 256), dim3(256), 0, stream>>>(W1, W2, W1t, W2t);
  scatter_kernel<<<dim3(NEDGES / 4), dim3(256), 0, stream>>>(x, row, col, nki, nkj, out);
  // GEMM1: Hb = relu(out @ W1 + b1)   [M=50048 tiles, K=512, N=1024], A f32 guarded at 50000
  gemm_kernel<false, true><<<dim3(MPAD / 128, H1 / 128), dim3(256), 0, stream>>>(
      out, W1t, b1, Hb, NNODES, D, H1);
  // GEMM2: out = Hb @ W2 + b2         [M=50048 tiles, K=1024, N=512], store guarded at 50000
  gemm_kernel<true, false><<<dim3(MPAD / 128, D / 128), dim3(256), 0, stream>>>(
      Hb, W2t, b2, out, NNODES, H1, D);
}

// Round 2
// 507.882 us; speedup vs baseline: 1.9272x; 1.9272x over previous
//
#include <hip/hip_runtime.h>

#define D 512
#define H1 1024
#define NNODES 50000
#define NEDGES 400000
#define MPAD 50048   // 391 * 128
#define NEG_SLOPE 0.2f
#define SCAN_BLOCKS 196   // 196*256 = 50176 >= 50000

typedef __attribute__((ext_vector_type(8))) short bf16x8;
typedef __attribute__((ext_vector_type(4))) float f32x4;
typedef __attribute__((ext_vector_type(4))) unsigned int u32x4;

__device__ __forceinline__ unsigned short f2bf(float f) {
  unsigned int u = __float_as_uint(f);
  unsigned int r = u + 0x7FFFu + ((u >> 16) & 1u);
  return (unsigned short)(r >> 16);
}

// key[j] = sum_i cond[i] * Wk[i][j],  Wk is (256, 2D) row-major
__global__ void key_kernel(const float* __restrict__ cond, const float* __restrict__ Wk,
                           float* __restrict__ key) {
  int j = blockIdx.x * blockDim.x + threadIdx.x;
  if (j >= 2 * D) return;
  float s = 0.f;
#pragma unroll 8
  for (int i = 0; i < 256; ++i) s += cond[i] * Wk[i * (2 * D) + j];
  key[j] = s;
}

// nki[n] = x[n] . key[0:D] ; nkj[n] = x[n] . key[D:2D]  (one wave per node)
__global__ void nodedot_kernel(const float* __restrict__ x, const float* __restrict__ key,
                               float* __restrict__ nki, float* __restrict__ nkj) {
  int wid = (blockIdx.x * blockDim.x + threadIdx.x) >> 6;
  int lane = threadIdx.x & 63;
  if (wid >= NNODES) return;
  const float* xr = x + (size_t)wid * D;
  float a = 0.f, b = 0.f;
#pragma unroll
  for (int k = 0; k < D / 64; ++k) {
    int idx = lane + k * 64;
    float v = xr[idx];
    a += v * key[idx];
    b += v * key[D + idx];
  }
#pragma unroll
  for (int off = 32; off > 0; off >>= 1) {
    a += __shfl_xor(a, off);
    b += __shfl_xor(b, off);
  }
  if (lane == 0) { nki[wid] = a; nkj[wid] = b; }
}

// W1 (D,2D) -> W1t (2D,D) bf16 ; W2 (2D,D) -> W2t (D,2D) bf16   (N x K layouts)
__global__ void convw_kernel(const float* __restrict__ W1, const float* __restrict__ W2,
                             unsigned short* __restrict__ W1t, unsigned short* __restrict__ W2t) {
  int idx = blockIdx.x * blockDim.x + threadIdx.x;
  if (idx >= D * H1) return;
  { int k = idx / H1, n = idx % H1; W1t[(size_t)n * D + k] = f2bf(W1[idx]); }
  { int k = idx / D,  n = idx % D;  W2t[(size_t)n * H1 + k] = f2bf(W2[idx]); }
}

// ---- CSR build ----
__global__ void zero_deg_kernel(int* __restrict__ deg) {
  int i = blockIdx.x * blockDim.x + threadIdx.x;
  if (i < NNODES) deg[i] = 0;
}

__global__ void hist_kernel(const int* __restrict__ row, int* __restrict__ deg) {
  int e = blockIdx.x * blockDim.x + threadIdx.x;
  if (e < NEDGES) atomicAdd(&deg[row[e]], 1);
}

// per-block exclusive scan of deg -> rowptr (block-local), block totals -> blktot
__global__ void scan1_kernel(const int* __restrict__ deg, int* __restrict__ rowptr,
                             int* __restrict__ blktot) {
  __shared__ int s[256];
  int tid = threadIdx.x;
  int i = blockIdx.x * 256 + tid;
  int v = (i < NNODES) ? deg[i] : 0;
  s[tid] = v;
  __syncthreads();
#pragma unroll
  for (int off = 1; off < 256; off <<= 1) {
    int t = (tid >= off) ? s[tid - off] : 0;
    __syncthreads();
    s[tid] += t;
    __syncthreads();
  }
  if (i < NNODES) rowptr[i] = s[tid] - v;  // exclusive within block
  if (tid == 255) blktot[blockIdx.x] = s[255];
}

// exclusive scan of block totals (196 values, one block)
__global__ void scan2_kernel(int* __restrict__ blktot, int* __restrict__ blkoff) {
  __shared__ int s[256];
  int tid = threadIdx.x;
  int v = (tid < SCAN_BLOCKS) ? blktot[tid] : 0;
  s[tid] = v;
  __syncthreads();
#pragma unroll
  for (int off = 1; off < 256; off <<= 1) {
    int t = (tid >= off) ? s[tid - off] : 0;
    __syncthreads();
    s[tid] += t;
    __syncthreads();
  }
  if (tid < SCAN_BLOCKS) blkoff[tid] = s[tid] - v;
}

// rowptr[i] += blkoff[blk]; cursor[i] = rowptr[i]; rowptr[NNODES] = NEDGES
__global__ void scan3_kernel(int* __restrict__ rowptr, const int* __restrict__ blkoff,
                             int* __restrict__ cursor) {
  int i = blockIdx.x * blockDim.x + threadIdx.x;
  if (i < NNODES) {
    int v = rowptr[i] + blkoff[blockIdx.x];
    rowptr[i] = v;
    cursor[i] = v;
  }
  if (i == 0) rowptr[NNODES] = NEDGES;
}

// per edge: alpha = sigmoid(leaky(nki[col]+nkj[row])); place (col,alpha) into CSR slot
__global__ void fill_kernel(const int* __restrict__ row, const int* __restrict__ col,
                            const float* __restrict__ nki, const float* __restrict__ nkj,
                            int* __restrict__ cursor, int* __restrict__ scol,
                            float* __restrict__ salpha) {
  int e = blockIdx.x * blockDim.x + threadIdx.x;
  if (e >= NEDGES) return;
  int r = row[e], c = col[e];
  float a = nki[c] + nkj[r];
  a = (a >= 0.f) ? a : NEG_SLOPE * a;
  float al = 1.f / (1.f + expf(-a));
  int pos = atomicAdd(&cursor[r], 1);
  scol[pos] = c;
  salpha[pos] = al;
}

// one wave per node: out[n] = x[n] + sum_e alpha_e * x[scol[e]]
__global__ __launch_bounds__(256) void agg_kernel(
    const float* __restrict__ x, const int* __restrict__ rowptr,
    const int* __restrict__ scol, const float* __restrict__ salpha,
    float* __restrict__ out) {
  int n = (blockIdx.x * blockDim.x + threadIdx.x) >> 6;
  int lane = threadIdx.x & 63;
  if (n >= NNODES) return;
  int beg = rowptr[n], end = rowptr[n + 1];
  float a0 = 0.f, a1 = 0.f, a2 = 0.f, a3 = 0.f;
  float b0 = 0.f, b1 = 0.f, b2 = 0.f, b3 = 0.f;
  for (int e = beg; e < end; ++e) {
    int c = scol[e];
    float al = salpha[e];
    const float4* xc = (const float4*)(x + (size_t)c * D);
    float4 v0 = xc[lane];
    float4 v1 = xc[64 + lane];
    a0 += al * v0.x; a1 += al * v0.y; a2 += al * v0.z; a3 += al * v0.w;
    b0 += al * v1.x; b1 += al * v1.y; b2 += al * v1.z; b3 += al * v1.w;
  }
  const float4* xn = (const float4*)(x + (size_t)n * D);
  float4 s0 = xn[lane], s1 = xn[64 + lane];
  float4 o0 = {s0.x + a0, s0.y + a1, s0.z + a2, s0.w + a3};
  float4 o1 = {s1.x + b0, s1.y + b1, s1.z + b2, s1.w + b3};
  float4* od = (float4*)(out + (size_t)n * D);
  od[lane] = o0;
  od[64 + lane] = o1;
}

// C = act(A @ Bt^T + bias). A: MxK row-major (f32 or bf16). Bt: NxK bf16 row-major.
// Tile 128x128, BK=32, 4 waves (2x2), each wave 64x64 = 4x4 tiles of 16x16x32 MFMA.
template <bool A_BF16, bool RELU_OUT_BF16>
__global__ __launch_bounds__(256) void gemm_kernel(
    const void* __restrict__ Aptr, const unsigned short* __restrict__ Bt,
    const float* __restrict__ bias, void* __restrict__ Cptr, int M_valid, int K, int N) {
  constexpr int BKP = 40;  // +8 pad breaks LDS bank conflicts
  __shared__ unsigned short As[128][BKP];
  __shared__ unsigned short Bs[128][BKP];

  const int tid = threadIdx.x;
  const int lane = tid & 63;
  const int wave = tid >> 6;
  const int wm = (wave >> 1) * 64;
  const int wn = (wave & 1) * 64;
  const int m0 = blockIdx.x * 128;
  const int n0 = blockIdx.y * 128;
  const int srow = tid >> 1;           // 0..127
  const int shalf = (tid & 1) * 16;    // 0 or 16 (k offset)
  const int fr = lane & 15;
  const int kg = (lane >> 4) * 8;

  f32x4 acc[4][4];
#pragma unroll
  for (int i = 0; i < 4; ++i)
#pragma unroll
    for (int j = 0; j < 4; ++j)
#pragma unroll
      for (int r = 0; r < 4; ++r) acc[i][j][r] = 0.f;

  for (int k0 = 0; k0 < K; k0 += 32) {
    {  // stage A tile [128][32]
      int gm = m0 + srow;
      if constexpr (A_BF16) {
        const unsigned short* Ah = (const unsigned short*)Aptr;
        const u32x4* s = (const u32x4*)(Ah + (size_t)gm * K + k0 + shalf);
        *(u32x4*)&As[srow][shalf] = s[0];
        *(u32x4*)&As[srow][shalf + 8] = s[1];
      } else {
        const float* Af = (const float*)Aptr;
        alignas(16) unsigned short h[16];
        if (gm < M_valid) {
          const float4* s4 = (const float4*)(Af + (size_t)gm * K + k0 + shalf);
#pragma unroll
          for (int q = 0; q < 4; ++q) {
            float4 f = s4[q];
            h[q * 4 + 0] = f2bf(f.x); h[q * 4 + 1] = f2bf(f.y);
            h[q * 4 + 2] = f2bf(f.z); h[q * 4 + 3] = f2bf(f.w);
          }
        } else {
#pragma unroll
          for (int q = 0; q < 16; ++q) h[q] = 0;
        }
        *(u32x4*)&As[srow][shalf] = *(const u32x4*)&h[0];
        *(u32x4*)&As[srow][shalf + 8] = *(const u32x4*)&h[8];
      }
      // stage B tile [128 n][32 k] from Bt (NxK)
      int gn = n0 + srow;
      const u32x4* s = (const u32x4*)(Bt + (size_t)gn * K + k0 + shalf);
      *(u32x4*)&Bs[srow][shalf] = s[0];
      *(u32x4*)&Bs[srow][shalf + 8] = s[1];
    }
    __syncthreads();

    bf16x8 a_frag[4], b_frag[4];
#pragma unroll
    for (int i = 0; i < 4; ++i) a_frag[i] = *(const bf16x8*)&As[wm + i * 16 + fr][kg];
#pragma unroll
    for (int j = 0; j < 4; ++j) b_frag[j] = *(const bf16x8*)&Bs[wn + j * 16 + fr][kg];
#pragma unroll
    for (int i = 0; i < 4; ++i)
#pragma unroll
      for (int j = 0; j < 4; ++j)
        acc[i][j] = __builtin_amdgcn_mfma_f32_16x16x32_bf16(a_frag[i], b_frag[j], acc[i][j], 0, 0, 0);
    __syncthreads();
  }

  // epilogue: C/D layout col = lane&15, row = (lane>>4)*4 + reg  [verified mapping]
  const int rg = (lane >> 4) * 4;
#pragma unroll
  for (int i = 0; i < 4; ++i) {
#pragma unroll
    for (int j = 0; j < 4; ++j) {
      int gn = n0 + wn + j * 16 + fr;
      float bv = bias[gn];
#pragma unroll
      for (int r = 0; r < 4; ++r) {
        int gm = m0 + wm + i * 16 + rg + r;
        float v = acc[i][j][r] + bv;
        if constexpr (RELU_OUT_BF16) {
          v = fmaxf(v, 0.f);
          ((unsigned short*)Cptr)[(size_t)gm * N + gn] = f2bf(v);
        } else {
          if (gm < M_valid) ((float*)Cptr)[(size_t)gm * N + gn] = v;
        }
      }
    }
  }
}

extern "C" void kernel_launch(void* const* d_in, const int* in_sizes, int n_in,
                              void* d_out, int out_size, void* d_ws, size_t ws_size,
                              hipStream_t stream) {
  const float* x    = (const float*)d_in[0];
  const int*   ei   = (const int*)d_in[1];
  const float* cond = (const float*)d_in[2];
  const float* Wk   = (const float*)d_in[3];
  const float* W1   = (const float*)d_in[4];
  const float* b1   = (const float*)d_in[5];
  const float* W2   = (const float*)d_in[6];
  const float* b2   = (const float*)d_in[7];
  float* out = (float*)d_out;

  char* ws = (char*)d_ws;
  size_t off = 0;
  auto alloc = [&](size_t b) { size_t p = off; off += (b + 255) & ~(size_t)255; return p; };
  float* key = (float*)(ws + alloc(2 * D * sizeof(float)));
  float* nki = (float*)(ws + alloc(NNODES * sizeof(float)));
  float* nkj = (float*)(ws + alloc(NNODES * sizeof(float)));
  int* deg    = (int*)(ws + alloc(NNODES * sizeof(int)));
  int* rowptr = (int*)(ws + alloc((NNODES + 1) * sizeof(int)));
  int* cursor = (int*)(ws + alloc(NNODES * sizeof(int)));
  int* blktot = (int*)(ws + alloc(SCAN_BLOCKS * sizeof(int)));
  int* blkoff = (int*)(ws + alloc(SCAN_BLOCKS * sizeof(int)));
  int* scol      = (int*)(ws + alloc(NEDGES * sizeof(int)));
  float* salpha  = (float*)(ws + alloc(NEDGES * sizeof(float)));
  unsigned short* W1t = (unsigned short*)(ws + alloc((size_t)H1 * D * 2));      // (2D, D)
  unsigned short* W2t = (unsigned short*)(ws + alloc((size_t)D * H1 * 2));      // (D, 2D)
  unsigned short* Hb  = (unsigned short*)(ws + alloc((size_t)MPAD * H1 * 2));   // hidden, bf16

  const int* row = ei;
  const int* col = ei + NEDGES;

  key_kernel<<<dim3((2 * D + 255) / 256), dim3(256), 0, stream>>>(cond, Wk, key);
  nodedot_kernel<<<dim3(NNODES * 64 / 256), dim3(256), 0, stream>>>(x, key, nki, nkj);
  convw_kernel<<<dim3(D * H1 / 256), dim3(256), 0, stream>>>(W1, W2, W1t, W2t);

  // CSR build
  zero_deg_kernel<<<dim3(SCAN_BLOCKS), dim3(256), 0, stream>>>(deg);
  hist_kernel<<<dim3((NEDGES + 255) / 256), dim3(256), 0, stream>>>(row, deg);
  scan1_kernel<<<dim3(SCAN_BLOCKS), dim3(256), 0, stream>>>(deg, rowptr, blktot);
  scan2_kernel<<<dim3(1), dim3(256), 0, stream>>>(blktot, blkoff);
  scan3_kernel<<<dim3(SCAN_BLOCKS), dim3(256), 0, stream>>>(rowptr, blkoff, cursor);
  fill_kernel<<<dim3((NEDGES + 255) / 256), dim3(256), 0, stream>>>(row, col, nki, nkj,
                                                                    cursor, scol, salpha);
  // aggregate: out = x + segment_sum(alpha * x[col])
  agg_kernel<<<dim3(NNODES * 64 / 256 + 1), dim3(256), 0, stream>>>(x, rowptr, scol, salpha, out);

  // GEMM1: Hb = relu(out @ W1 + b1)   [M=50048 tiles, K=512, N=1024], A f32 guarded at 50000
  gemm_kernel<false, true><<<dim3(MPAD / 128, H1 / 128), dim3(256), 0, stream>>>(
      out, W1t, b1, Hb, NNODES, D, H1);
  // GEMM2: out = Hb @ W2 + b2         [M=50048 tiles, K=1024, N=512], store guarded at 50000
  gemm_kernel<true, false><<<dim3(MPAD / 128, D / 128), dim3(256), 0, stream>>>(
      Hb, W2t, b2, out, NNODES, H1, D);
}

// Round 3
// 499.430 us; speedup vs baseline: 1.9598x; 1.0169x over previous
//
#include <hip/hip_runtime.h>

#define D 512
#define H1 1024
#define NNODES 50000
#define NEDGES 400000
#define MPAD 50048   // 391 * 128
#define NEG_SLOPE 0.2f
#define SCAN_BLOCKS 196   // 196*256 = 50176 >= 50000

typedef __attribute__((ext_vector_type(8))) short bf16x8;
typedef __attribute__((ext_vector_type(4))) float f32x4;

__device__ __forceinline__ unsigned short f2bf(float f) {
  unsigned int u = __float_as_uint(f);
  unsigned int r = u + 0x7FFFu + ((u >> 16) & 1u);
  return (unsigned short)(r >> 16);
}

__device__ __forceinline__ void gl_lds16(const void* g, void* l) {
  __builtin_amdgcn_global_load_lds(
      (const __attribute__((address_space(1))) void*)g,
      (__attribute__((address_space(3))) void*)l, 16, 0, 0);
}

// key[j] = sum_i cond[i] * Wk[i][j],  Wk is (256, 2D) row-major
__global__ void key_kernel(const float* __restrict__ cond, const float* __restrict__ Wk,
                           float* __restrict__ key) {
  int j = blockIdx.x * blockDim.x + threadIdx.x;
  if (j >= 2 * D) return;
  float s = 0.f;
#pragma unroll 8
  for (int i = 0; i < 256; ++i) s += cond[i] * Wk[i * (2 * D) + j];
  key[j] = s;
}

// nki[n] = x[n] . key[0:D] ; nkj[n] = x[n] . key[D:2D]  (one wave per node)
__global__ void nodedot_kernel(const float* __restrict__ x, const float* __restrict__ key,
                               float* __restrict__ nki, float* __restrict__ nkj) {
  int wid = (blockIdx.x * blockDim.x + threadIdx.x) >> 6;
  int lane = threadIdx.x & 63;
  if (wid >= NNODES) return;
  const float* xr = x + (size_t)wid * D;
  float a = 0.f, b = 0.f;
#pragma unroll
  for (int k = 0; k < D / 64; ++k) {
    int idx = lane + k * 64;
    float v = xr[idx];
    a += v * key[idx];
    b += v * key[D + idx];
  }
#pragma unroll
  for (int off = 32; off > 0; off >>= 1) {
    a += __shfl_xor(a, off);
    b += __shfl_xor(b, off);
  }
  if (lane == 0) { nki[wid] = a; nkj[wid] = b; }
}

// W1 (D,2D) -> W1t (2D,D) bf16 ; W2 (2D,D) -> W2t (D,2D) bf16   (N x K layouts)
__global__ void convw_kernel(const float* __restrict__ W1, const float* __restrict__ W2,
                             unsigned short* __restrict__ W1t, unsigned short* __restrict__ W2t) {
  int idx = blockIdx.x * blockDim.x + threadIdx.x;
  if (idx >= D * H1) return;
  { int k = idx / H1, n = idx % H1; W1t[(size_t)n * D + k] = f2bf(W1[idx]); }
  { int k = idx / D,  n = idx % D;  W2t[(size_t)n * H1 + k] = f2bf(W2[idx]); }
}

// ---- CSR build ----
__global__ void zero_deg_kernel(int* __restrict__ deg) {
  int i = blockIdx.x * blockDim.x + threadIdx.x;
  if (i < NNODES) deg[i] = 0;
}

__global__ void hist_kernel(const int* __restrict__ row, int* __restrict__ deg) {
  int e = blockIdx.x * blockDim.x + threadIdx.x;
  if (e < NEDGES) atomicAdd(&deg[row[e]], 1);
}

__global__ void scan1_kernel(const int* __restrict__ deg, int* __restrict__ rowptr,
                             int* __restrict__ blktot) {
  __shared__ int s[256];
  int tid = threadIdx.x;
  int i = blockIdx.x * 256 + tid;
  int v = (i < NNODES) ? deg[i] : 0;
  s[tid] = v;
  __syncthreads();
#pragma unroll
  for (int off = 1; off < 256; off <<= 1) {
    int t = (tid >= off) ? s[tid - off] : 0;
    __syncthreads();
    s[tid] += t;
    __syncthreads();
  }
  if (i < NNODES) rowptr[i] = s[tid] - v;
  if (tid == 255) blktot[blockIdx.x] = s[255];
}

__global__ void scan2_kernel(int* __restrict__ blktot, int* __restrict__ blkoff) {
  __shared__ int s[256];
  int tid = threadIdx.x;
  int v = (tid < SCAN_BLOCKS) ? blktot[tid] : 0;
  s[tid] = v;
  __syncthreads();
#pragma unroll
  for (int off = 1; off < 256; off <<= 1) {
    int t = (tid >= off) ? s[tid - off] : 0;
    __syncthreads();
    s[tid] += t;
    __syncthreads();
  }
  if (tid < SCAN_BLOCKS) blkoff[tid] = s[tid] - v;
}

__global__ void scan3_kernel(int* __restrict__ rowptr, const int* __restrict__ blkoff,
                             int* __restrict__ cursor) {
  int i = blockIdx.x * blockDim.x + threadIdx.x;
  if (i < NNODES) {
    int v = rowptr[i] + blkoff[blockIdx.x];
    rowptr[i] = v;
    cursor[i] = v;
  }
  if (i == 0) rowptr[NNODES] = NEDGES;
}

// per edge: alpha = sigmoid(leaky(nki[col]+nkj[row])); place (col,alpha) into CSR slot
__global__ void fill_kernel(const int* __restrict__ row, const int* __restrict__ col,
                            const float* __restrict__ nki, const float* __restrict__ nkj,
                            int* __restrict__ cursor, int* __restrict__ scol,
                            float* __restrict__ salpha) {
  int e = blockIdx.x * blockDim.x + threadIdx.x;
  if (e >= NEDGES) return;
  int r = row[e], c = col[e];
  float a = nki[c] + nkj[r];
  a = (a >= 0.f) ? a : NEG_SLOPE * a;
  float al = 1.f / (1.f + expf(-a));
  int pos = atomicAdd(&cursor[r], 1);
  scol[pos] = c;
  salpha[pos] = al;
}

// one wave per node: Pb[n] = bf16(x[n] + sum_e alpha_e * x[scol[e]])
__global__ __launch_bounds__(256) void agg_kernel(
    const float* __restrict__ x, const int* __restrict__ rowptr,
    const int* __restrict__ scol, const float* __restrict__ salpha,
    unsigned short* __restrict__ Pb) {
  int n = (blockIdx.x * blockDim.x + threadIdx.x) >> 6;
  int lane = threadIdx.x & 63;
  if (n >= NNODES) return;
  int beg = rowptr[n], end = rowptr[n + 1];
  float a0 = 0.f, a1 = 0.f, a2 = 0.f, a3 = 0.f;
  float b0 = 0.f, b1 = 0.f, b2 = 0.f, b3 = 0.f;
  for (int e = beg; e < end; ++e) {
    int c = scol[e];
    float al = salpha[e];
    const float4* xc = (const float4*)(x + (size_t)c * D);
    float4 v0 = xc[lane];
    float4 v1 = xc[64 + lane];
    a0 += al * v0.x; a1 += al * v0.y; a2 += al * v0.z; a3 += al * v0.w;
    b0 += al * v1.x; b1 += al * v1.y; b2 += al * v1.z; b3 += al * v1.w;
  }
  const float4* xn = (const float4*)(x + (size_t)n * D);
  float4 s0 = xn[lane], s1 = xn[64 + lane];
  ushort4 h0 = {f2bf(s0.x + a0), f2bf(s0.y + a1), f2bf(s0.z + a2), f2bf(s0.w + a3)};
  ushort4 h1 = {f2bf(s1.x + b0), f2bf(s1.y + b1), f2bf(s1.z + b2), f2bf(s1.w + b3)};
  ushort4* od = (ushort4*)(Pb + (size_t)n * D);
  od[lane] = h0;
  od[64 + lane] = h1;
}

// C = act(A @ Bt^T + bias). A: MxK bf16 row-major (M padded to 128). Bt: NxK bf16.
// m97 structure: tile 128x128, BK=64, global_load_lds x16 into chunked LDS
// [kc][row][8] (linear, conflict-free 2-way reads), 4 waves 2x2, 16x16x32 MFMA.
// grid = (N/128, M/128): x = n fastest so same-m blocks share the A panel in L2.
template <bool RELU_OUT_BF16>
__global__ __launch_bounds__(256) void gemm_kernel(
    const unsigned short* __restrict__ Ag, const unsigned short* __restrict__ Bt,
    const float* __restrict__ bias, void* __restrict__ Cptr, int M_valid, int K, int N) {
  __shared__ unsigned short As[8 * 128 * 8];  // [kc 0..7][row 0..127][8], 16 KB
  __shared__ unsigned short Bs[8 * 128 * 8];

  const int tid = threadIdx.x;
  const int lane = tid & 63;
  const int wave = tid >> 6;
  const int wm = (wave >> 1) * 64;
  const int wn = (wave & 1) * 64;
  const int n0 = blockIdx.x * 128;
  const int m0 = blockIdx.y * 128;
  const int fr = lane & 15;
  const int kq = lane >> 4;  // 0..3

  f32x4 acc[4][4];
#pragma unroll
  for (int i = 0; i < 4; ++i)
#pragma unroll
    for (int j = 0; j < 4; ++j)
#pragma unroll
      for (int r = 0; r < 4; ++r) acc[i][j][r] = 0.f;

  for (int k0 = 0; k0 < K; k0 += 64) {
    // stage: 16 segments each of A and B; wave w takes segments w*4..w*4+3.
    // segment s covers LDS entries s*64+l  (entry = kc*128+row, kc=s>>1, row=(s&1)*64+l)
#pragma unroll
    for (int ss = 0; ss < 4; ++ss) {
      int s = wave * 4 + ss;
      int rbase = (s & 1) * 64;
      int kc = s >> 1;
      gl_lds16(Ag + (size_t)(m0 + rbase + lane) * K + k0 + kc * 8, &As[s * 512]);
      gl_lds16(Bt + (size_t)(n0 + rbase + lane) * K + k0 + kc * 8, &Bs[s * 512]);
    }
    __syncthreads();

#pragma unroll
    for (int h = 0; h < 2; ++h) {
      const int kc = h * 4 + kq;
      bf16x8 af[4], bfr[4];
#pragma unroll
      for (int i = 0; i < 4; ++i)
        af[i] = *(const bf16x8*)&As[(kc * 128 + wm + i * 16 + fr) * 8];
#pragma unroll
      for (int j = 0; j < 4; ++j)
        bfr[j] = *(const bf16x8*)&Bs[(kc * 128 + wn + j * 16 + fr) * 8];
#pragma unroll
      for (int i = 0; i < 4; ++i)
#pragma unroll
        for (int j = 0; j < 4; ++j)
          acc[i][j] = __builtin_amdgcn_mfma_f32_16x16x32_bf16(af[i], bfr[j], acc[i][j], 0, 0, 0);
    }
    __syncthreads();
  }

  // epilogue: C/D layout col = lane&15, row = (lane>>4)*4 + reg
  const int rg = kq * 4;
#pragma unroll
  for (int i = 0; i < 4; ++i) {
#pragma unroll
    for (int j = 0; j < 4; ++j) {
      int gn = n0 + wn + j * 16 + fr;
      float bv = bias[gn];
#pragma unroll
      for (int r = 0; r < 4; ++r) {
        int gm = m0 + wm + i * 16 + rg + r;
        float v = acc[i][j][r] + bv;
        if constexpr (RELU_OUT_BF16) {
          v = fmaxf(v, 0.f);
          ((unsigned short*)Cptr)[(size_t)gm * N + gn] = f2bf(v);
        } else {
          if (gm < M_valid) ((float*)Cptr)[(size_t)gm * N + gn] = v;
        }
      }
    }
  }
}

extern "C" void kernel_launch(void* const* d_in, const int* in_sizes, int n_in,
                              void* d_out, int out_size, void* d_ws, size_t ws_size,
                              hipStream_t stream) {
  const float* x    = (const float*)d_in[0];
  const int*   ei   = (const int*)d_in[1];
  const float* cond = (const float*)d_in[2];
  const float* Wk   = (const float*)d_in[3];
  const float* W1   = (const float*)d_in[4];
  const float* b1   = (const float*)d_in[5];
  const float* W2   = (const float*)d_in[6];
  const float* b2   = (const float*)d_in[7];
  float* out = (float*)d_out;

  char* ws = (char*)d_ws;
  size_t off = 0;
  auto alloc = [&](size_t b) { size_t p = off; off += (b + 255) & ~(size_t)255; return p; };
  float* key = (float*)(ws + alloc(2 * D * sizeof(float)));
  float* nki = (float*)(ws + alloc(NNODES * sizeof(float)));
  float* nkj = (float*)(ws + alloc(NNODES * sizeof(float)));
  int* deg    = (int*)(ws + alloc(NNODES * sizeof(int)));
  int* rowptr = (int*)(ws + alloc((NNODES + 1) * sizeof(int)));
  int* cursor = (int*)(ws + alloc(NNODES * sizeof(int)));
  int* blktot = (int*)(ws + alloc(SCAN_BLOCKS * sizeof(int)));
  int* blkoff = (int*)(ws + alloc(SCAN_BLOCKS * sizeof(int)));
  int* scol      = (int*)(ws + alloc(NEDGES * sizeof(int)));
  float* salpha  = (float*)(ws + alloc(NEDGES * sizeof(float)));
  unsigned short* W1t = (unsigned short*)(ws + alloc((size_t)H1 * D * 2));      // (2D, D)
  unsigned short* W2t = (unsigned short*)(ws + alloc((size_t)D * H1 * 2));      // (D, 2D)
  unsigned short* Pb  = (unsigned short*)(ws + alloc((size_t)MPAD * D * 2));    // P, bf16
  unsigned short* Hb  = (unsigned short*)(ws + alloc((size_t)MPAD * H1 * 2));   // hidden, bf16

  const int* row = ei;
  const int* col = ei + NEDGES;

  key_kernel<<<dim3((2 * D + 255) / 256), dim3(256), 0, stream>>>(cond, Wk, key);
  nodedot_kernel<<<dim3(NNODES * 64 / 256), dim3(256), 0, stream>>>(x, key, nki, nkj);
  convw_kernel<<<dim3(D * H1 / 256), dim3(256), 0, stream>>>(W1, W2, W1t, W2t);

  // CSR build
  zero_deg_kernel<<<dim3(SCAN_BLOCKS), dim3(256), 0, stream>>>(deg);
  hist_kernel<<<dim3((NEDGES + 255) / 256), dim3(256), 0, stream>>>(row, deg);
  scan1_kernel<<<dim3(SCAN_BLOCKS), dim3(256), 0, stream>>>(deg, rowptr, blktot);
  scan2_kernel<<<dim3(1), dim3(256), 0, stream>>>(blktot, blkoff);
  scan3_kernel<<<dim3(SCAN_BLOCKS), dim3(256), 0, stream>>>(rowptr, blkoff, cursor);
  fill_kernel<<<dim3((NEDGES + 255) / 256), dim3(256), 0, stream>>>(row, col, nki, nkj,
                                                                    cursor, scol, salpha);
  // aggregate: Pb = bf16(x + segment_sum(alpha * x[col]))
  agg_kernel<<<dim3(NNODES * 64 / 256 + 1), dim3(256), 0, stream>>>(x, rowptr, scol, salpha, Pb);

  // GEMM1: Hb = relu(Pb @ W1 + b1)   [M=50048, K=512, N=1024]
  gemm_kernel<true><<<dim3(H1 / 128, MPAD / 128), dim3(256), 0, stream>>>(
      Pb, W1t, b1, Hb, NNODES, D, H1);
  // GEMM2: out = Hb @ W2 + b2        [M=50048, K=1024, N=512], store guarded at 50000
  gemm_kernel<false><<<dim3(D / 128, MPAD / 128), dim3(256), 0, stream>>>(
      Hb, W2t, b2, out, NNODES, H1, D);
}

// Round 4
// 438.255 us; speedup vs baseline: 2.2333x; 1.1396x over previous
//
#include <hip/hip_runtime.h>

#define D 512
#define H1 1024
#define NNODES 50000
#define NEDGES 400000
#define MPAD 50048   // 391 * 128
#define NEG_SLOPE 0.2f
#define SCAN_BLOCKS 196   // 196*256 = 50176 >= 50000

typedef __attribute__((ext_vector_type(8))) short bf16x8;
typedef __attribute__((ext_vector_type(8))) unsigned short u16x8;
typedef __attribute__((ext_vector_type(4))) float f32x4;

// packed operand layout for GEMM staging:
// addr(r, k) = ((r>>7)*(K>>3) + (k>>3))*1024 + (r&127)*8 + (k&7)
// -> a 64-lane global_load_lds segment (rows rbase..rbase+63, one 8-k chunk)
//    is a single contiguous 1KB burst.

__device__ __forceinline__ unsigned short f2bf(float f) {
  unsigned int u = __float_as_uint(f);
  unsigned int r = u + 0x7FFFu + ((u >> 16) & 1u);
  return (unsigned short)(r >> 16);
}

__device__ __forceinline__ void gl_lds16(const void* g, void* l) {
  __builtin_amdgcn_global_load_lds(
      (const __attribute__((address_space(1))) void*)g,
      (__attribute__((address_space(3))) void*)l, 16, 0, 0);
}

// key[j] = sum_i cond[i] * Wk[i][j],  Wk is (256, 2D) row-major
__global__ void key_kernel(const float* __restrict__ cond, const float* __restrict__ Wk,
                           float* __restrict__ key) {
  int j = blockIdx.x * blockDim.x + threadIdx.x;
  if (j >= 2 * D) return;
  float s = 0.f;
#pragma unroll 8
  for (int i = 0; i < 256; ++i) s += cond[i] * Wk[i * (2 * D) + j];
  key[j] = s;
}

// nki[n] = x[n] . key[0:D] ; nkj[n] = x[n] . key[D:2D]  (one wave per node)
__global__ void nodedot_kernel(const float* __restrict__ x, const float* __restrict__ key,
                               float* __restrict__ nki, float* __restrict__ nkj) {
  int wid = (blockIdx.x * blockDim.x + threadIdx.x) >> 6;
  int lane = threadIdx.x & 63;
  if (wid >= NNODES) return;
  const float* xr = x + (size_t)wid * D;
  float a = 0.f, b = 0.f;
#pragma unroll
  for (int k = 0; k < D / 64; ++k) {
    int idx = lane + k * 64;
    float v = xr[idx];
    a += v * key[idx];
    b += v * key[D + idx];
  }
#pragma unroll
  for (int off = 32; off > 0; off >>= 1) {
    a += __shfl_xor(a, off);
    b += __shfl_xor(b, off);
  }
  if (lane == 0) { nki[wid] = a; nkj[wid] = b; }
}

// W1 (D,2D) -> W1t packed (R=H1, K=D) ; W2 (2D,D) -> W2t packed (R=D, K=H1)
__global__ void convw_kernel(const float* __restrict__ W1, const float* __restrict__ W2,
                             unsigned short* __restrict__ W1t, unsigned short* __restrict__ W2t) {
  int idx = blockIdx.x * blockDim.x + threadIdx.x;
  if (idx >= D * H1) return;
  {
    int k = idx / H1, n = idx % H1;
    size_t a = (((size_t)(n >> 7) * (D >> 3) + (k >> 3)) << 10) + ((n & 127) << 3) + (k & 7);
    W1t[a] = f2bf(W1[idx]);
  }
  {
    int k = idx / D, n = idx % D;
    size_t a = (((size_t)(n >> 7) * (H1 >> 3) + (k >> 3)) << 10) + ((n & 127) << 3) + (k & 7);
    W2t[a] = f2bf(W2[idx]);
  }
}

// ---- CSR build ----
__global__ void zero_deg_kernel(int* __restrict__ deg) {
  int i = blockIdx.x * blockDim.x + threadIdx.x;
  if (i < NNODES) deg[i] = 0;
}

__global__ void hist_kernel(const int* __restrict__ row, int* __restrict__ deg) {
  int e = blockIdx.x * blockDim.x + threadIdx.x;
  if (e < NEDGES) atomicAdd(&deg[row[e]], 1);
}

__global__ void scan1_kernel(const int* __restrict__ deg, int* __restrict__ rowptr,
                             int* __restrict__ blktot) {
  __shared__ int s[256];
  int tid = threadIdx.x;
  int i = blockIdx.x * 256 + tid;
  int v = (i < NNODES) ? deg[i] : 0;
  s[tid] = v;
  __syncthreads();
#pragma unroll
  for (int off = 1; off < 256; off <<= 1) {
    int t = (tid >= off) ? s[tid - off] : 0;
    __syncthreads();
    s[tid] += t;
    __syncthreads();
  }
  if (i < NNODES) rowptr[i] = s[tid] - v;
  if (tid == 255) blktot[blockIdx.x] = s[255];
}

__global__ void scan2_kernel(int* __restrict__ blktot, int* __restrict__ blkoff) {
  __shared__ int s[256];
  int tid = threadIdx.x;
  int v = (tid < SCAN_BLOCKS) ? blktot[tid] : 0;
  s[tid] = v;
  __syncthreads();
#pragma unroll
  for (int off = 1; off < 256; off <<= 1) {
    int t = (tid >= off) ? s[tid - off] : 0;
    __syncthreads();
    s[tid] += t;
    __syncthreads();
  }
  if (tid < SCAN_BLOCKS) blkoff[tid] = s[tid] - v;
}

__global__ void scan3_kernel(int* __restrict__ rowptr, const int* __restrict__ blkoff,
                             int* __restrict__ cursor) {
  int i = blockIdx.x * blockDim.x + threadIdx.x;
  if (i < NNODES) {
    int v = rowptr[i] + blkoff[blockIdx.x];
    rowptr[i] = v;
    cursor[i] = v;
  }
  if (i == 0) rowptr[NNODES] = NEDGES;
}

// per edge: alpha = sigmoid(leaky(nki[col]+nkj[row])); place (col,alpha) into CSR slot
__global__ void fill_kernel(const int* __restrict__ row, const int* __restrict__ col,
                            const float* __restrict__ nki, const float* __restrict__ nkj,
                            int* __restrict__ cursor, int* __restrict__ scol,
                            float* __restrict__ salpha) {
  int e = blockIdx.x * blockDim.x + threadIdx.x;
  if (e >= NEDGES) return;
  int r = row[e], c = col[e];
  float a = nki[c] + nkj[r];
  a = (a >= 0.f) ? a : NEG_SLOPE * a;
  float al = 1.f / (1.f + expf(-a));
  int pos = atomicAdd(&cursor[r], 1);
  scol[pos] = c;
  salpha[pos] = al;
}

// one wave per node: Pb[n] = bf16(x[n] + sum_e alpha_e * x[scol[e]]), packed layout.
// lane owns k = 8*lane .. 8*lane+7  (reads 32B/lane coalesced; one ushort8 write)
__global__ __launch_bounds__(256) void agg_kernel(
    const float* __restrict__ x, const int* __restrict__ rowptr,
    const int* __restrict__ scol, const float* __restrict__ salpha,
    unsigned short* __restrict__ Pb) {
  int n = (blockIdx.x * blockDim.x + threadIdx.x) >> 6;
  int lane = threadIdx.x & 63;
  if (n >= NNODES) return;
  int beg = rowptr[n], end = rowptr[n + 1];
  const float4* xn = (const float4*)(x + (size_t)n * D);
  float4 v0 = xn[2 * lane], v1 = xn[2 * lane + 1];
  float s[8] = {v0.x, v0.y, v0.z, v0.w, v1.x, v1.y, v1.z, v1.w};
  for (int e = beg; e < end; ++e) {
    int c = scol[e];
    float al = salpha[e];
    const float4* xc = (const float4*)(x + (size_t)c * D);
    float4 w0 = xc[2 * lane], w1 = xc[2 * lane + 1];
    s[0] += al * w0.x; s[1] += al * w0.y; s[2] += al * w0.z; s[3] += al * w0.w;
    s[4] += al * w1.x; s[5] += al * w1.y; s[6] += al * w1.z; s[7] += al * w1.w;
  }
  u16x8 h;
#pragma unroll
  for (int q = 0; q < 8; ++q) h[q] = f2bf(s[q]);
  // packed addr: ((n>>7)*(D>>3) + lane)*1024 + (n&127)*8
  *(u16x8*)(Pb + (((size_t)(n >> 7) * (D >> 3) + lane) << 10) + ((n & 127) << 3)) = h;
}

// C = act(A @ Bt^T + bias). A, Bt in PACKED layout (see top). M padded to 128.
// m97 structure: tile 128x128, BK=64, coalesced global_load_lds x16 into linear
// chunked LDS [kc][row][8], 4 waves 2x2, 16x16x32 MFMA.
// grid = (N/128, M/128): n fastest so same-m blocks share the A panel in L2.
// RELU_OUT_BF16: C written packed bf16 (K'=N). else: C written row-major f32, guarded.
template <bool RELU_OUT_BF16>
__global__ __launch_bounds__(256) void gemm_kernel(
    const unsigned short* __restrict__ Ag, const unsigned short* __restrict__ Bt,
    const float* __restrict__ bias, void* __restrict__ Cptr, int M_valid, int K, int N) {
  __shared__ unsigned short As[8 * 128 * 8];  // [kc 0..7][row 0..127][8], 16 KB
  __shared__ unsigned short Bs[8 * 128 * 8];

  const int tid = threadIdx.x;
  const int lane = tid & 63;
  const int wave = tid >> 6;
  const int wm = (wave >> 1) * 64;
  const int wn = (wave & 1) * 64;
  const int n0 = blockIdx.x * 128;
  const int fr = lane & 15;
  const int kq = lane >> 4;  // 0..3

  // packed panels for this block's m-tile / n-tile
  const unsigned short* Apan = Ag + ((size_t)blockIdx.y * (K >> 3) << 10);
  const unsigned short* Bpan = Bt + ((size_t)blockIdx.x * (K >> 3) << 10);

  f32x4 acc[4][4];
#pragma unroll
  for (int i = 0; i < 4; ++i)
#pragma unroll
    for (int j = 0; j < 4; ++j)
#pragma unroll
      for (int r = 0; r < 4; ++r) acc[i][j][r] = 0.f;

  for (int k0 = 0; k0 < K; k0 += 64) {
    // 16 segments each; wave w takes segments w*4..w*4+3.
    // segment s: kc = s>>1, rows (s&1)*64 .. +63 -> one contiguous 1KB burst.
#pragma unroll
    for (int ss = 0; ss < 4; ++ss) {
      int s = wave * 4 + ss;
      int rbase = (s & 1) * 64;
      int kca = (k0 >> 3) + (s >> 1);
      gl_lds16(Apan + ((size_t)kca << 10) + (rbase + lane) * 8, &As[s * 512]);
      gl_lds16(Bpan + ((size_t)kca << 10) + (rbase + lane) * 8, &Bs[s * 512]);
    }
    __syncthreads();

#pragma unroll
    for (int h = 0; h < 2; ++h) {
      const int kc = h * 4 + kq;
      bf16x8 af[4], bfr[4];
#pragma unroll
      for (int i = 0; i < 4; ++i)
        af[i] = *(const bf16x8*)&As[(kc * 128 + wm + i * 16 + fr) * 8];
#pragma unroll
      for (int j = 0; j < 4; ++j)
        bfr[j] = *(const bf16x8*)&Bs[(kc * 128 + wn + j * 16 + fr) * 8];
#pragma unroll
      for (int i = 0; i < 4; ++i)
#pragma unroll
        for (int j = 0; j < 4; ++j)
          acc[i][j] = __builtin_amdgcn_mfma_f32_16x16x32_bf16(af[i], bfr[j], acc[i][j], 0, 0, 0);
    }
    __syncthreads();
  }

  // epilogue: C/D layout col = lane&15, row = (lane>>4)*4 + reg
  const int rg = kq * 4;
#pragma unroll
  for (int i = 0; i < 4; ++i) {
#pragma unroll
    for (int j = 0; j < 4; ++j) {
      int gn = n0 + wn + j * 16 + fr;
      float bv = bias[gn];
#pragma unroll
      for (int r = 0; r < 4; ++r) {
        int lr = wm + i * 16 + rg + r;  // row within tile (= gm & 127)
        float v = acc[i][j][r] + bv;
        if constexpr (RELU_OUT_BF16) {
          v = fmaxf(v, 0.f);
          size_t a = (((size_t)blockIdx.y * (N >> 3) + (gn >> 3)) << 10) + (lr << 3) + (gn & 7);
          ((unsigned short*)Cptr)[a] = f2bf(v);
        } else {
          int gm = blockIdx.y * 128 + lr;
          if (gm < M_valid) ((float*)Cptr)[(size_t)gm * N + gn] = v;
        }
      }
    }
  }
}

extern "C" void kernel_launch(void* const* d_in, const int* in_sizes, int n_in,
                              void* d_out, int out_size, void* d_ws, size_t ws_size,
                              hipStream_t stream) {
  const float* x    = (const float*)d_in[0];
  const int*   ei   = (const int*)d_in[1];
  const float* cond = (const float*)d_in[2];
  const float* Wk   = (const float*)d_in[3];
  const float* W1   = (const float*)d_in[4];
  const float* b1   = (const float*)d_in[5];
  const float* W2   = (const float*)d_in[6];
  const float* b2   = (const float*)d_in[7];
  float* out = (float*)d_out;

  char* ws = (char*)d_ws;
  size_t off = 0;
  auto alloc = [&](size_t b) { size_t p = off; off += (b + 255) & ~(size_t)255; return p; };
  float* key = (float*)(ws + alloc(2 * D * sizeof(float)));
  float* nki = (float*)(ws + alloc(NNODES * sizeof(float)));
  float* nkj = (float*)(ws + alloc(NNODES * sizeof(float)));
  int* deg    = (int*)(ws + alloc(NNODES * sizeof(int)));
  int* rowptr = (int*)(ws + alloc((NNODES + 1) * sizeof(int)));
  int* cursor = (int*)(ws + alloc(NNODES * sizeof(int)));
  int* blktot = (int*)(ws + alloc(SCAN_BLOCKS * sizeof(int)));
  int* blkoff = (int*)(ws + alloc(SCAN_BLOCKS * sizeof(int)));
  int* scol      = (int*)(ws + alloc(NEDGES * sizeof(int)));
  float* salpha  = (float*)(ws + alloc(NEDGES * sizeof(float)));
  unsigned short* W1t = (unsigned short*)(ws + alloc((size_t)H1 * D * 2));      // packed (R=H1,K=D)
  unsigned short* W2t = (unsigned short*)(ws + alloc((size_t)D * H1 * 2));      // packed (R=D,K=H1)
  unsigned short* Pb  = (unsigned short*)(ws + alloc((size_t)MPAD * D * 2));    // packed (R=MPAD,K=D)
  unsigned short* Hb  = (unsigned short*)(ws + alloc((size_t)MPAD * H1 * 2));   // packed (R=MPAD,K=H1)

  const int* row = ei;
  const int* col = ei + NEDGES;

  key_kernel<<<dim3((2 * D + 255) / 256), dim3(256), 0, stream>>>(cond, Wk, key);
  nodedot_kernel<<<dim3(NNODES * 64 / 256), dim3(256), 0, stream>>>(x, key, nki, nkj);
  convw_kernel<<<dim3(D * H1 / 256), dim3(256), 0, stream>>>(W1, W2, W1t, W2t);

  // CSR build
  zero_deg_kernel<<<dim3(SCAN_BLOCKS), dim3(256), 0, stream>>>(deg);
  hist_kernel<<<dim3((NEDGES + 255) / 256), dim3(256), 0, stream>>>(row, deg);
  scan1_kernel<<<dim3(SCAN_BLOCKS), dim3(256), 0, stream>>>(deg, rowptr, blktot);
  scan2_kernel<<<dim3(1), dim3(256), 0, stream>>>(blktot, blkoff);
  scan3_kernel<<<dim3(SCAN_BLOCKS), dim3(256), 0, stream>>>(rowptr, blkoff, cursor);
  fill_kernel<<<dim3((NEDGES + 255) / 256), dim3(256), 0, stream>>>(row, col, nki, nkj,
                                                                    cursor, scol, salpha);
  // aggregate: Pb = bf16(x + segment_sum(alpha * x[col])), packed
  agg_kernel<<<dim3(NNODES * 64 / 256 + 1), dim3(256), 0, stream>>>(x, rowptr, scol, salpha, Pb);

  // GEMM1: Hb = relu(Pb @ W1 + b1)   [M=50048, K=512, N=1024]
  gemm_kernel<true><<<dim3(H1 / 128, MPAD / 128), dim3(256), 0, stream>>>(
      Pb, W1t, b1, Hb, NNODES, D, H1);
  // GEMM2: out = Hb @ W2 + b2        [M=50048, K=1024, N=512], store guarded at 50000
  gemm_kernel<false><<<dim3(D / 128, MPAD / 128), dim3(256), 0, stream>>>(
      Hb, W2t, b2, out, NNODES, H1, D);
}

// Round 5
// 360.572 us; speedup vs baseline: 2.7145x; 1.2154x over previous
//
#include <hip/hip_runtime.h>

#define D 512
#define H1 1024
#define NNODES 50000
#define NEDGES 400000
#define MPAD 50048   // 391 * 128
#define NEG_SLOPE 0.2f
#define SCAN_BLOCKS 196   // 196*256 = 50176 >= 50000

typedef __attribute__((ext_vector_type(8))) short bf16x8;
typedef __attribute__((ext_vector_type(8))) unsigned short u16x8;
typedef __attribute__((ext_vector_type(4))) float f32x4;

// packed operand layout for GEMM staging:
// addr(r, k) = ((r>>7)*(K>>3) + (k>>3))*1024 + (r&127)*8 + (k&7)
// -> a 64-lane global_load_lds segment (rows rbase..rbase+63, one 8-k chunk)
//    is a single contiguous 1KB burst.

__device__ __forceinline__ unsigned short f2bf(float f) {
  unsigned int u = __float_as_uint(f);
  unsigned int r = u + 0x7FFFu + ((u >> 16) & 1u);
  return (unsigned short)(r >> 16);
}
__device__ __forceinline__ float bf2f(unsigned short h) {
  return __uint_as_float((unsigned int)h << 16);
}

__device__ __forceinline__ void gl_lds16(const void* g, void* l) {
  __builtin_amdgcn_global_load_lds(
      (const __attribute__((address_space(1))) void*)g,
      (__attribute__((address_space(3))) void*)l, 16, 0, 0);
}

// key[j] = sum_i cond[i] * Wk[i][j],  Wk is (256, 2D) row-major
__global__ void key_kernel(const float* __restrict__ cond, const float* __restrict__ Wk,
                           float* __restrict__ key) {
  int j = blockIdx.x * blockDim.x + threadIdx.x;
  if (j >= 2 * D) return;
  float s = 0.f;
#pragma unroll 8
  for (int i = 0; i < 256; ++i) s += cond[i] * Wk[i * (2 * D) + j];
  key[j] = s;
}

// one wave per node: nki/nkj dots + emit xb = bf16(x) row-major.
// lane owns k = 8*lane..8*lane+7 (32B/lane reads, one 16B xb write).
__global__ void nodedot_kernel(const float* __restrict__ x, const float* __restrict__ key,
                               float* __restrict__ nki, float* __restrict__ nkj,
                               unsigned short* __restrict__ xb) {
  int wid = (blockIdx.x * blockDim.x + threadIdx.x) >> 6;
  int lane = threadIdx.x & 63;
  if (wid >= NNODES) return;
  const float4* xr = (const float4*)(x + (size_t)wid * D);
  float4 p0 = xr[2 * lane], p1 = xr[2 * lane + 1];
  const float4* kia = (const float4*)key;
  const float4* kja = (const float4*)(key + D);
  float4 q0 = kia[2 * lane], q1 = kia[2 * lane + 1];
  float4 r0 = kja[2 * lane], r1 = kja[2 * lane + 1];
  float a = p0.x * q0.x + p0.y * q0.y + p0.z * q0.z + p0.w * q0.w +
            p1.x * q1.x + p1.y * q1.y + p1.z * q1.z + p1.w * q1.w;
  float b = p0.x * r0.x + p0.y * r0.y + p0.z * r0.z + p0.w * r0.w +
            p1.x * r1.x + p1.y * r1.y + p1.z * r1.z + p1.w * r1.w;
  u16x8 h;
  h[0] = f2bf(p0.x); h[1] = f2bf(p0.y); h[2] = f2bf(p0.z); h[3] = f2bf(p0.w);
  h[4] = f2bf(p1.x); h[5] = f2bf(p1.y); h[6] = f2bf(p1.z); h[7] = f2bf(p1.w);
  *(u16x8*)(xb + (size_t)wid * D + 8 * lane) = h;
#pragma unroll
  for (int off = 32; off > 0; off >>= 1) {
    a += __shfl_xor(a, off);
    b += __shfl_xor(b, off);
  }
  if (lane == 0) { nki[wid] = a; nkj[wid] = b; }
}

// W1 (D,2D) -> W1t packed (R=H1, K=D) ; W2 (2D,D) -> W2t packed (R=D, K=H1)
__global__ void convw_kernel(const float* __restrict__ W1, const float* __restrict__ W2,
                             unsigned short* __restrict__ W1t, unsigned short* __restrict__ W2t) {
  int idx = blockIdx.x * blockDim.x + threadIdx.x;
  if (idx >= D * H1) return;
  {
    int k = idx / H1, n = idx % H1;
    size_t a = (((size_t)(n >> 7) * (D >> 3) + (k >> 3)) << 10) + ((n & 127) << 3) + (k & 7);
    W1t[a] = f2bf(W1[idx]);
  }
  {
    int k = idx / D, n = idx % D;
    size_t a = (((size_t)(n >> 7) * (H1 >> 3) + (k >> 3)) << 10) + ((n & 127) << 3) + (k & 7);
    W2t[a] = f2bf(W2[idx]);
  }
}

// ---- CSR build ----
__global__ void zero_deg_kernel(int* __restrict__ deg) {
  int i = blockIdx.x * blockDim.x + threadIdx.x;
  if (i < NNODES) deg[i] = 0;
}

__global__ void hist_kernel(const int* __restrict__ row, int* __restrict__ deg) {
  int e = blockIdx.x * blockDim.x + threadIdx.x;
  if (e < NEDGES) atomicAdd(&deg[row[e]], 1);
}

__global__ void scan1_kernel(const int* __restrict__ deg, int* __restrict__ rowptr,
                             int* __restrict__ blktot) {
  __shared__ int s[256];
  int tid = threadIdx.x;
  int i = blockIdx.x * 256 + tid;
  int v = (i < NNODES) ? deg[i] : 0;
  s[tid] = v;
  __syncthreads();
#pragma unroll
  for (int off = 1; off < 256; off <<= 1) {
    int t = (tid >= off) ? s[tid - off] : 0;
    __syncthreads();
    s[tid] += t;
    __syncthreads();
  }
  if (i < NNODES) rowptr[i] = s[tid] - v;
  if (tid == 255) blktot[blockIdx.x] = s[255];
}

__global__ void scan2_kernel(int* __restrict__ blktot, int* __restrict__ blkoff) {
  __shared__ int s[256];
  int tid = threadIdx.x;
  int v = (tid < SCAN_BLOCKS) ? blktot[tid] : 0;
  s[tid] = v;
  __syncthreads();
#pragma unroll
  for (int off = 1; off < 256; off <<= 1) {
    int t = (tid >= off) ? s[tid - off] : 0;
    __syncthreads();
    s[tid] += t;
    __syncthreads();
  }
  if (tid < SCAN_BLOCKS) blkoff[tid] = s[tid] - v;
}

__global__ void scan3_kernel(int* __restrict__ rowptr, const int* __restrict__ blkoff,
                             int* __restrict__ cursor) {
  int i = blockIdx.x * blockDim.x + threadIdx.x;
  if (i < NNODES) {
    int v = rowptr[i] + blkoff[blockIdx.x];
    rowptr[i] = v;
    cursor[i] = v;
  }
  if (i == 0) rowptr[NNODES] = NEDGES;
}

// per edge: alpha = sigmoid(leaky(nki[col]+nkj[row])); place (col,alpha) into CSR slot
__global__ void fill_kernel(const int* __restrict__ row, const int* __restrict__ col,
                            const float* __restrict__ nki, const float* __restrict__ nkj,
                            int* __restrict__ cursor, int* __restrict__ scol,
                            float* __restrict__ salpha) {
  int e = blockIdx.x * blockDim.x + threadIdx.x;
  if (e >= NEDGES) return;
  int r = row[e], c = col[e];
  float a = nki[c] + nkj[r];
  a = (a >= 0.f) ? a : NEG_SLOPE * a;
  float al = 1.f / (1.f + expf(-a));
  int pos = atomicAdd(&cursor[r], 1);
  scol[pos] = c;
  salpha[pos] = al;
}

// one wave per node: Pb[n] = bf16(xb[n] + sum_e alpha_e * xb[scol[e]]), packed out.
// bf16 gathers (16B/lane), edge loop unrolled x2 (two independent gather chains).
__global__ __launch_bounds__(256) void agg_kernel(
    const unsigned short* __restrict__ xb, const int* __restrict__ rowptr,
    const int* __restrict__ scol, const float* __restrict__ salpha,
    unsigned short* __restrict__ Pb) {
  int n = (blockIdx.x * blockDim.x + threadIdx.x) >> 6;
  int lane = threadIdx.x & 63;
  if (n >= NNODES) return;
  int beg = rowptr[n], end = rowptr[n + 1];
  u16x8 self = *(const u16x8*)(xb + (size_t)n * D + 8 * lane);
  float sa[8], sb[8];
#pragma unroll
  for (int q = 0; q < 8; ++q) { sa[q] = bf2f(self[q]); sb[q] = 0.f; }
  int e = beg;
  for (; e + 1 < end; e += 2) {
    int c0 = scol[e], c1 = scol[e + 1];
    float al0 = salpha[e], al1 = salpha[e + 1];
    u16x8 w0 = *(const u16x8*)(xb + (size_t)c0 * D + 8 * lane);
    u16x8 w1 = *(const u16x8*)(xb + (size_t)c1 * D + 8 * lane);
#pragma unroll
    for (int q = 0; q < 8; ++q) {
      sa[q] += al0 * bf2f(w0[q]);
      sb[q] += al1 * bf2f(w1[q]);
    }
  }
  if (e < end) {
    int c0 = scol[e];
    float al0 = salpha[e];
    u16x8 w0 = *(const u16x8*)(xb + (size_t)c0 * D + 8 * lane);
#pragma unroll
    for (int q = 0; q < 8; ++q) sa[q] += al0 * bf2f(w0[q]);
  }
  u16x8 h;
#pragma unroll
  for (int q = 0; q < 8; ++q) h[q] = f2bf(sa[q] + sb[q]);
  // packed addr: ((n>>7)*(D>>3) + lane)*1024 + (n&127)*8
  *(u16x8*)(Pb + (((size_t)(n >> 7) * (D >> 3) + lane) << 10) + ((n & 127) << 3)) = h;
}

// C = act(A @ Bt^T + bias). A, Bt in PACKED layout (see top). M padded to 128.
// m97 structure + bijective XCD-chunked block swizzle (same-panel blocks -> same XCD L2).
template <bool RELU_OUT_BF16>
__global__ __launch_bounds__(256) void gemm_kernel(
    const unsigned short* __restrict__ Ag, const unsigned short* __restrict__ Bt,
    const float* __restrict__ bias, void* __restrict__ Cptr, int M_valid, int K, int N) {
  __shared__ unsigned short As[8 * 128 * 8];  // [kc 0..7][row 0..127][8], 16 KB
  __shared__ unsigned short Bs[8 * 128 * 8];

  // XCD-aware bijective swizzle (m204 form): consecutive logical ids -> same XCD
  const int G = gridDim.x * gridDim.y;
  const int orig = blockIdx.y * gridDim.x + blockIdx.x;
  const int qq = G >> 3, rr = G & 7;
  const int xcd = orig & 7, loc = orig >> 3;
  const int wg = (xcd < rr ? xcd * (qq + 1) : rr * (qq + 1) + (xcd - rr) * qq) + loc;
  const int bx = wg % gridDim.x;
  const int by = wg / gridDim.x;

  const int tid = threadIdx.x;
  const int lane = tid & 63;
  const int wave = tid >> 6;
  const int wm = (wave >> 1) * 64;
  const int wn = (wave & 1) * 64;
  const int n0 = bx * 128;
  const int fr = lane & 15;
  const int kq = lane >> 4;  // 0..3

  // packed panels for this block's m-tile / n-tile
  const unsigned short* Apan = Ag + ((size_t)by * (K >> 3) << 10);
  const unsigned short* Bpan = Bt + ((size_t)bx * (K >> 3) << 10);

  f32x4 acc[4][4];
#pragma unroll
  for (int i = 0; i < 4; ++i)
#pragma unroll
    for (int j = 0; j < 4; ++j)
#pragma unroll
      for (int r = 0; r < 4; ++r) acc[i][j][r] = 0.f;

  for (int k0 = 0; k0 < K; k0 += 64) {
    // 16 segments each; wave w takes segments w*4..w*4+3.
    // segment s: kc = s>>1, rows (s&1)*64 .. +63 -> one contiguous 1KB burst.
#pragma unroll
    for (int ss = 0; ss < 4; ++ss) {
      int s = wave * 4 + ss;
      int rbase = (s & 1) * 64;
      int kca = (k0 >> 3) + (s >> 1);
      gl_lds16(Apan + ((size_t)kca << 10) + (rbase + lane) * 8, &As[s * 512]);
      gl_lds16(Bpan + ((size_t)kca << 10) + (rbase + lane) * 8, &Bs[s * 512]);
    }
    __syncthreads();

#pragma unroll
    for (int h = 0; h < 2; ++h) {
      const int kc = h * 4 + kq;
      bf16x8 af[4], bfr[4];
#pragma unroll
      for (int i = 0; i < 4; ++i)
        af[i] = *(const bf16x8*)&As[(kc * 128 + wm + i * 16 + fr) * 8];
#pragma unroll
      for (int j = 0; j < 4; ++j)
        bfr[j] = *(const bf16x8*)&Bs[(kc * 128 + wn + j * 16 + fr) * 8];
#pragma unroll
      for (int i = 0; i < 4; ++i)
#pragma unroll
        for (int j = 0; j < 4; ++j)
          acc[i][j] = __builtin_amdgcn_mfma_f32_16x16x32_bf16(af[i], bfr[j], acc[i][j], 0, 0, 0);
    }
    __syncthreads();
  }

  // epilogue: C/D layout col = lane&15, row = (lane>>4)*4 + reg
  const int rg = kq * 4;
#pragma unroll
  for (int i = 0; i < 4; ++i) {
#pragma unroll
    for (int j = 0; j < 4; ++j) {
      int gn = n0 + wn + j * 16 + fr;
      float bv = bias[gn];
#pragma unroll
      for (int r = 0; r < 4; ++r) {
        int lr = wm + i * 16 + rg + r;  // row within tile (= gm & 127)
        float v = acc[i][j][r] + bv;
        if constexpr (RELU_OUT_BF16) {
          v = fmaxf(v, 0.f);
          size_t a = (((size_t)by * (N >> 3) + (gn >> 3)) << 10) + (lr << 3) + (gn & 7);
          ((unsigned short*)Cptr)[a] = f2bf(v);
        } else {
          int gm = by * 128 + lr;
          if (gm < M_valid) ((float*)Cptr)[(size_t)gm * N + gn] = v;
        }
      }
    }
  }
}

extern "C" void kernel_launch(void* const* d_in, const int* in_sizes, int n_in,
                              void* d_out, int out_size, void* d_ws, size_t ws_size,
                              hipStream_t stream) {
  const float* x    = (const float*)d_in[0];
  const int*   ei   = (const int*)d_in[1];
  const float* cond = (const float*)d_in[2];
  const float* Wk   = (const float*)d_in[3];
  const float* W1   = (const float*)d_in[4];
  const float* b1   = (const float*)d_in[5];
  const float* W2   = (const float*)d_in[6];
  const float* b2   = (const float*)d_in[7];
  float* out = (float*)d_out;

  char* ws = (char*)d_ws;
  size_t off = 0;
  auto alloc = [&](size_t b) { size_t p = off; off += (b + 255) & ~(size_t)255; return p; };
  float* key = (float*)(ws + alloc(2 * D * sizeof(float)));
  float* nki = (float*)(ws + alloc(NNODES * sizeof(float)));
  float* nkj = (float*)(ws + alloc(NNODES * sizeof(float)));
  int* deg    = (int*)(ws + alloc(NNODES * sizeof(int)));
  int* rowptr = (int*)(ws + alloc((NNODES + 1) * sizeof(int)));
  int* cursor = (int*)(ws + alloc(NNODES * sizeof(int)));
  int* blktot = (int*)(ws + alloc(SCAN_BLOCKS * sizeof(int)));
  int* blkoff = (int*)(ws + alloc(SCAN_BLOCKS * sizeof(int)));
  int* scol      = (int*)(ws + alloc(NEDGES * sizeof(int)));
  float* salpha  = (float*)(ws + alloc(NEDGES * sizeof(float)));
  unsigned short* xb  = (unsigned short*)(ws + alloc((size_t)NNODES * D * 2));  // bf16 x, row-major
  unsigned short* W1t = (unsigned short*)(ws + alloc((size_t)H1 * D * 2));      // packed (R=H1,K=D)
  unsigned short* W2t = (unsigned short*)(ws + alloc((size_t)D * H1 * 2));      // packed (R=D,K=H1)
  unsigned short* Pb  = (unsigned short*)(ws + alloc((size_t)MPAD * D * 2));    // packed (R=MPAD,K=D)
  unsigned short* Hb  = (unsigned short*)(ws + alloc((size_t)MPAD * H1 * 2));   // packed (R=MPAD,K=H1)

  const int* row = ei;
  const int* col = ei + NEDGES;

  key_kernel<<<dim3((2 * D + 255) / 256), dim3(256), 0, stream>>>(cond, Wk, key);
  nodedot_kernel<<<dim3(NNODES * 64 / 256), dim3(256), 0, stream>>>(x, key, nki, nkj, xb);
  convw_kernel<<<dim3(D * H1 / 256), dim3(256), 0, stream>>>(W1, W2, W1t, W2t);

  // CSR build
  zero_deg_kernel<<<dim3(SCAN_BLOCKS), dim3(256), 0, stream>>>(deg);
  hist_kernel<<<dim3((NEDGES + 255) / 256), dim3(256), 0, stream>>>(row, deg);
  scan1_kernel<<<dim3(SCAN_BLOCKS), dim3(256), 0, stream>>>(deg, rowptr, blktot);
  scan2_kernel<<<dim3(1), dim3(256), 0, stream>>>(blktot, blkoff);
  scan3_kernel<<<dim3(SCAN_BLOCKS), dim3(256), 0, stream>>>(rowptr, blkoff, cursor);
  fill_kernel<<<dim3((NEDGES + 255) / 256), dim3(256), 0, stream>>>(row, col, nki, nkj,
                                                                    cursor, scol, salpha);
  // aggregate: Pb = bf16(xb + segment_sum(alpha * xb[col])), packed
  agg_kernel<<<dim3(NNODES * 64 / 256 + 1), dim3(256), 0, stream>>>(xb, rowptr, scol, salpha, Pb);

  // GEMM1: Hb = relu(Pb @ W1 + b1)   [M=50048, K=512, N=1024]
  gemm_kernel<true><<<dim3(H1 / 128, MPAD / 128), dim3(256), 0, stream>>>(
      Pb, W1t, b1, Hb, NNODES, D, H1);
  // GEMM2: out = Hb @ W2 + b2        [M=50048, K=1024, N=512], store guarded at 50000
  gemm_kernel<false><<<dim3(D / 128, MPAD / 128), dim3(256), 0, stream>>>(
      Hb, W2t, b2, out, NNODES, H1, D);
}